// Round 3
// baseline (671.265 us; speedup 1.0000x reference)
//
#include <hip/hip_runtime.h>

#define NCOLS 256
#define NP    128
#define DD    256

typedef _Float16 half2 __attribute__((ext_vector_type(2)));
typedef _Float16 half4 __attribute__((ext_vector_type(4)));
typedef float    f32x4 __attribute__((ext_vector_type(4)));

// gfx950 spelling has no underscore before f16 (compiler-confirmed)
#define MFMA16(a,b,c) __builtin_amdgcn_mfma_f32_16x16x16f16(a,b,c,0,0,0)

// ---- workspace layout (bytes) ----
#define WS_COL_LN   0          // f32 [256][256]  LN(emb_column)
#define WS_LNP      262144     // f32 [128][256]  LN(emb_prompt)
#define WS_BASE     393216     // f32 [128][256]  base (prompt-side xp part)
#define WS_BLOG     524288     // f32 [128][256]  base_logits
#define WS_CW16     655360     // f16 [256][256]  CW = col_ln @ W2   (row n, col k)
#define WS_WB16     786432     // half2 [256][256] {w,b} interleaved feature emb

// ---- main-kernel LDS layout ----
#define XE_STRIDE 68           // f16 units; row byte stride 136 (8B aligned)
#define XE0_OFF   3072
#define XE1_OFF   37888
#define SMEM_BYTES 72704       // 2 blocks/CU (145408 <= 163840)

// ============================ stage 0 kernels ============================

__global__ __launch_bounds__(256) void k0a(
    const float* __restrict__ emb_column, const float* __restrict__ emb_prompt,
    const float* __restrict__ ln_col_g, const float* __restrict__ ln_col_b,
    const float* __restrict__ ln_prompt_g, const float* __restrict__ ln_prompt_b,
    const float* __restrict__ few, const float* __restrict__ feb, char* __restrict__ ws)
{
    __shared__ float red[10];
    int blk = blockIdx.x, tid = threadIdx.x;
    if (blk < 384) {
        const float *src, *g, *bb; float* dst;
        if (blk < 256) { int r = blk;     src = emb_column + r*DD; g = ln_col_g;    bb = ln_col_b;    dst = (float*)(ws + WS_COL_LN) + r*DD; }
        else           { int r = blk-256; src = emb_prompt + r*DD; g = ln_prompt_g; bb = ln_prompt_b; dst = (float*)(ws + WS_LNP) + r*DD; }
        float v = src[tid];
        float s = v, q = v*v;
        #pragma unroll
        for (int off = 32; off; off >>= 1) { s += __shfl_xor(s, off); q += __shfl_xor(q, off); }
        int wid = tid >> 6, lane = tid & 63;
        if (lane == 0) { red[wid] = s; red[4+wid] = q; }
        __syncthreads();
        if (tid == 0) {
            float S = red[0]+red[1]+red[2]+red[3];
            float Q = red[4]+red[5]+red[6]+red[7];
            float mu = S * (1.0f/DD);
            float var = Q * (1.0f/DD) - mu*mu;
            red[8] = mu; red[9] = rsqrtf(var + 1e-5f);
        }
        __syncthreads();
        dst[tid] = (v - red[8]) * red[9] * g[tid] + bb[tid];
    } else {
        int base = (blk - 384) * 512;
        half2* wb = (half2*)(ws + WS_WB16);
        #pragma unroll
        for (int j = 0; j < 2; ++j) {
            int idx = base + j*256 + tid;      // 0..65535
            half2 h; h[0] = (_Float16)few[idx]; h[1] = (_Float16)feb[idx];
            wb[idx] = h;
        }
    }
}

// blocks 0..255: CW[n][k] = sum_d col_ln[n][d] * diw[d][256+k]  (f16)
// blocks 256..383: base[p][d] = sum_k LNp[p][k]*diw[d][k] + dib[d] + emb_prompt[p][d]
__global__ __launch_bounds__(256) void k0b(
    const float* __restrict__ diw, const float* __restrict__ dib,
    const float* __restrict__ emb_prompt, char* __restrict__ ws)
{
    __shared__ float rowv[DD];
    int blk = blockIdx.x, tid = threadIdx.x;
    if (blk < 256) {
        int n = blk;
        const float* col_ln = (const float*)(ws + WS_COL_LN);
        rowv[tid] = col_ln[n*DD + tid];
        __syncthreads();
        float acc = 0.f;
        #pragma unroll 4
        for (int d = 0; d < DD; ++d) acc += rowv[d] * diw[d*512 + 256 + tid];
        ((_Float16*)(ws + WS_CW16))[n*DD + tid] = (_Float16)acc;
    } else {
        int p = blk - 256;
        const float* lnp = (const float*)(ws + WS_LNP);
        rowv[tid] = lnp[p*DD + tid];
        __syncthreads();
        float acc = 0.f;
        #pragma unroll 4
        for (int k = 0; k < DD; ++k) acc += rowv[k] * diw[tid*512 + k];
        ((float*)(ws + WS_BASE))[p*DD + tid] = acc + dib[tid] + emb_prompt[p*DD + tid];
    }
}

// base_logits[p][n] = sum_d base[p][d] * col_ln[n][d]
__global__ __launch_bounds__(256) void k0c(char* __restrict__ ws)
{
    __shared__ float bs[DD];
    int p = blockIdx.x, n = threadIdx.x;
    const float* base   = (const float*)(ws + WS_BASE);
    const float* col_ln = (const float*)(ws + WS_COL_LN);
    bs[n] = base[p*DD + n];
    __syncthreads();
    float acc = 0.f;
    #pragma unroll 4
    for (int d = 0; d < DD; ++d) acc += bs[d] * col_ln[n*DD + d];
    ((float*)(ws + WS_BLOG))[p*DD + n] = acc;
}

// ============================ main kernel ============================
// 1 block = 1 batch. 8 waves, wave w owns prompt tile p in [16w,16w+16).
// P1 (barrier-free): acc_l[nt] = logits^T tile via K=16 mfma(A=CW from L2, B=prev^T),
//     C initialized from base_logits.
// P2: softmax in-register (rows lane-local across lq: 2x shfl_xor), convert to f16.
//     acc_l layout (n=16nt+4lq+r, p=16w+lr) IS the K=16 B-fragment for P3 — no LDS.
// P3: acc_v[dt] = V^T tile via mfma(A=xe^T from LDS (dbuf, computed on the fly), B=P).
__global__ __launch_bounds__(512, 4) void trompt_main(
    const float* __restrict__ x, const float* __restrict__ prev,
    const float* __restrict__ expand_w, const float* __restrict__ expand_b,
    const float* __restrict__ ln_emb_g, const float* __restrict__ ln_emb_b,
    const char* __restrict__ ws, float* __restrict__ out)
{
    extern __shared__ char smem[];
    float* x_s  = (float*)(smem);
    float* g_s  = (float*)(smem + 1024);
    float* bb_s = (float*)(smem + 2048);
    _Float16* xe0 = (_Float16*)(smem + XE0_OFF);
    _Float16* xe1 = (_Float16*)(smem + XE1_OFF);

    const char*  CW16 = ws + WS_CW16;                      // f16 [n][k]
    const half2* WB   = (const half2*)(ws + WS_WB16);      // [n][d] {w,b}
    const float* blog = (const float*)(ws + WS_BLOG);

    int b = blockIdx.x;
    int tid = threadIdx.x;
    int w = tid >> 6, l = tid & 63, lq = l >> 4, lr = l & 15;

    // --- C-init from base_logits (deep-prefetched) ---
    f32x4 acc_l[16];
    {
        const float* blrow = blog + (16*w + lr)*DD + 4*lq;
        #pragma unroll
        for (int nt = 0; nt < 16; ++nt) acc_l[nt] = *(const f32x4*)(blrow + 16*nt);
    }

    if (tid < 256) {
        x_s[tid]  = x[b*NCOLS + tid];
        g_s[tid]  = ln_emb_g[tid];
        bb_s[tid] = ln_emb_b[tid];
    }
    __syncthreads();

    // ---------------- P1: logits^T += CW @ prev^T (K=16, barrier-free) ----------------
    {
        const char* cwlane = CW16 + lr*512 + lq*8;   // + nt*8192 + kc*32
        half4 af0[8], af1[8];
        #pragma unroll
        for (int i = 0; i < 8; ++i) af0[i] = *(const half4*)(cwlane + i*8192);
        #pragma unroll
        for (int i = 0; i < 8; ++i) af1[i] = *(const half4*)(cwlane + (8+i)*8192);

        const float* prow = prev + ((size_t)b*NP + 16*w + lr)*DD + 4*lq;
        f32x4 pb_c = *(const f32x4*)(prow);

        #pragma unroll
        for (int kc = 0; kc < 16; ++kc) {
            f32x4 pb_n;
            if (kc < 15) pb_n = *(const f32x4*)(prow + (kc+1)*16);
            half4 bp;
            #pragma unroll
            for (int j = 0; j < 4; ++j) bp[j] = (_Float16)pb_c[j];
            #pragma unroll
            for (int i = 0; i < 8; ++i) {
                half4 v = af0[i];
                if (kc < 15) af0[i] = *(const half4*)(cwlane + i*8192 + (kc+1)*32);
                acc_l[i] = MFMA16(v, bp, acc_l[i]);
            }
            #pragma unroll
            for (int i = 0; i < 8; ++i) {
                half4 v = af1[i];
                if (kc < 15) af1[i] = *(const half4*)(cwlane + (8+i)*8192 + (kc+1)*32);
                acc_l[8+i] = MFMA16(v, bp, acc_l[8+i]);
            }
            pb_c = pb_n;
        }
    }

    // x_emb tile compute (64 n-rows) into transposed LDS [d][n], 8 rows/wave.
    auto compute_xe = [&](int tile, _Float16* xb) {
        #pragma unroll
        for (int i = 0; i < 8; ++i) {
            int nloc = w + 8*i;
            int n = tile*64 + nloc;
            float xv = x_s[n];
            const half2* wbrow = WB + n*DD;
            float ev[4]; float s = 0.f, q = 0.f;
            #pragma unroll
            for (int c = 0; c < 4; ++c) {
                int d = l + 64*c;
                half2 p = wbrow[d];
                float e = fmaf(xv, (float)p[0], (float)p[1]);
                e = e > 0.f ? e : 0.f;
                ev[c] = e; s += e; q += e*e;
            }
            #pragma unroll
            for (int off = 32; off; off >>= 1) { s += __shfl_xor(s, off); q += __shfl_xor(q, off); }
            float mu = s * (1.0f/DD);
            float rs = rsqrtf(q*(1.0f/DD) - mu*mu + 1e-5f);
            #pragma unroll
            for (int c = 0; c < 4; ++c) {
                int d = l + 64*c;
                xb[d*XE_STRIDE + nloc] = (_Float16)((ev[c]-mu)*rs*g_s[d] + bb_s[d]);
            }
        }
    };

    // overlap xe tile-0 compute with softmax's shfl latency
    compute_xe(0, xe0);

    // ---------------- P2: softmax over n, normalize, convert to f16 B-fragments ----------------
    half4 p16[16];
    {
        float mx = -1e30f;
        #pragma unroll
        for (int nt = 0; nt < 16; ++nt)
            #pragma unroll
            for (int r = 0; r < 4; ++r) mx = fmaxf(mx, acc_l[nt][r]);
        mx = fmaxf(mx, __shfl_xor(mx, 16));
        mx = fmaxf(mx, __shfl_xor(mx, 32));
        float sum = 0.f;
        #pragma unroll
        for (int nt = 0; nt < 16; ++nt)
            #pragma unroll
            for (int r = 0; r < 4; ++r) { float e = __expf(acc_l[nt][r] - mx); acc_l[nt][r] = e; sum += e; }
        sum += __shfl_xor(sum, 16);
        sum += __shfl_xor(sum, 32);
        float inv = 1.0f / sum;
        #pragma unroll
        for (int nt = 0; nt < 16; ++nt) {
            half4 h;
            #pragma unroll
            for (int r = 0; r < 4; ++r) h[r] = (_Float16)(acc_l[nt][r] * inv);
            p16[nt] = h;
        }
    }
    __syncthreads();   // xe0 ready

    // ---------------- P3: V^T = xe^T @ P (K=16; xe tiles dbuf'd against MFMA) ----------------
    f32x4 acc_v[16];
    #pragma unroll
    for (int dt = 0; dt < 16; ++dt) acc_v[dt] = (f32x4){0.f,0.f,0.f,0.f};

    for (int t = 0; t < 4; ++t) {
        _Float16* xb = (t & 1) ? xe1 : xe0;
        if (t < 3) compute_xe(t+1, (t & 1) ? xe0 : xe1);
        #pragma unroll
        for (int kc2 = 0; kc2 < 4; ++kc2) {
            half4 bp = p16[4*t + kc2];
            #pragma unroll
            for (int dt = 0; dt < 16; ++dt) {
                half4 a = *(const half4*)(xb + (16*dt + lr)*XE_STRIDE + kc2*16 + lq*4);
                acc_v[dt] = MFMA16(a, bp, acc_v[dt]);
            }
        }
        __syncthreads();
    }

    // epilogue: D[d][p] orientation -> per-lane p uniform, f32x4 stores along d
    {
        int p = 16*w + lr;
        float sw = 1.0f + expand_w[p];
        float sb = expand_b[p];
        float* orow = out + ((size_t)b*NP + p)*DD + 4*lq;
        #pragma unroll
        for (int dt = 0; dt < 16; ++dt) {
            f32x4 v = acc_v[dt];
            #pragma unroll
            for (int r = 0; r < 4; ++r) v[r] = v[r]*sw + sb;
            *(f32x4*)(orow + 16*dt) = v;
        }
    }
}

// ============================ launcher ============================
extern "C" void kernel_launch(void* const* d_in, const int* in_sizes, int n_in,
                              void* d_out, int out_size, void* d_ws, size_t ws_size,
                              hipStream_t stream) {
    (void)in_sizes; (void)n_in; (void)out_size; (void)ws_size;
    const float* x           = (const float*)d_in[0];
    const float* prev        = (const float*)d_in[1];
    const float* few         = (const float*)d_in[2];
    const float* feb         = (const float*)d_in[3];
    const float* ln_emb_g    = (const float*)d_in[4];
    const float* ln_emb_b    = (const float*)d_in[5];
    const float* ln_col_g    = (const float*)d_in[6];
    const float* ln_col_b    = (const float*)d_in[7];
    const float* ln_prompt_g = (const float*)d_in[8];
    const float* ln_prompt_b = (const float*)d_in[9];
    const float* diw         = (const float*)d_in[10];
    const float* dib         = (const float*)d_in[11];
    const float* emb_column  = (const float*)d_in[12];
    const float* emb_prompt  = (const float*)d_in[13];
    const float* expand_w    = (const float*)d_in[14];
    const float* expand_b    = (const float*)d_in[15];
    char* ws = (char*)d_ws;
    float* out = (float*)d_out;

    k0a<<<512, 256, 0, stream>>>(emb_column, emb_prompt, ln_col_g, ln_col_b,
                                 ln_prompt_g, ln_prompt_b, few, feb, ws);
    k0b<<<384, 256, 0, stream>>>(diw, dib, emb_prompt, ws);
    k0c<<<128, 256, 0, stream>>>(ws);

    (void)hipFuncSetAttribute(reinterpret_cast<const void*>(trompt_main),
                              hipFuncAttributeMaxDynamicSharedMemorySize, SMEM_BYTES);
    trompt_main<<<1024, 512, SMEM_BYTES, stream>>>(x, prev, expand_w, expand_b,
                                                   ln_emb_g, ln_emb_b, ws, out);
}

// Round 4
// 596.826 us; speedup vs baseline: 1.1247x; 1.1247x over previous
//
#include <hip/hip_runtime.h>

#define NCOLS 256
#define NP    128
#define DD    256

typedef _Float16 half2 __attribute__((ext_vector_type(2)));
typedef _Float16 half4 __attribute__((ext_vector_type(4)));
typedef float    f32x4 __attribute__((ext_vector_type(4)));

// gfx950 spelling has no underscore before f16 (compiler-confirmed)
#define MFMA16(a,b,c) __builtin_amdgcn_mfma_f32_16x16x16f16(a,b,c,0,0,0)

// ---- workspace layout (bytes) ----
#define WS_COL_LN   0          // f32 [256][256]  LN(emb_column)
#define WS_LNP      262144     // f32 [128][256]  LN(emb_prompt)
#define WS_BASE     393216     // f32 [128][256]  base (prompt-side xp part)
#define WS_BLOG     524288     // f32 [128][256]  base_logits
#define WS_CW16     655360     // f16 [256][256]  CW = col_ln @ W2   (row n, col k)
#define WS_WB16     786432     // half2 [256][256] {w,b} interleaved feature emb

// ---- main-kernel LDS layout ----
#define XE_STRIDE 68           // f16 units; row byte stride 136 (8B aligned)
#define XE0_OFF   3072
#define XE1_OFF   37888
#define SMEM_BYTES 72704

// ============================ stage 0 kernels ============================

__global__ __launch_bounds__(256) void k0a(
    const float* __restrict__ emb_column, const float* __restrict__ emb_prompt,
    const float* __restrict__ ln_col_g, const float* __restrict__ ln_col_b,
    const float* __restrict__ ln_prompt_g, const float* __restrict__ ln_prompt_b,
    const float* __restrict__ few, const float* __restrict__ feb, char* __restrict__ ws)
{
    __shared__ float red[10];
    int blk = blockIdx.x, tid = threadIdx.x;
    if (blk < 384) {
        const float *src, *g, *bb; float* dst;
        if (blk < 256) { int r = blk;     src = emb_column + r*DD; g = ln_col_g;    bb = ln_col_b;    dst = (float*)(ws + WS_COL_LN) + r*DD; }
        else           { int r = blk-256; src = emb_prompt + r*DD; g = ln_prompt_g; bb = ln_prompt_b; dst = (float*)(ws + WS_LNP) + r*DD; }
        float v = src[tid];
        float s = v, q = v*v;
        #pragma unroll
        for (int off = 32; off; off >>= 1) { s += __shfl_xor(s, off); q += __shfl_xor(q, off); }
        int wid = tid >> 6, lane = tid & 63;
        if (lane == 0) { red[wid] = s; red[4+wid] = q; }
        __syncthreads();
        if (tid == 0) {
            float S = red[0]+red[1]+red[2]+red[3];
            float Q = red[4]+red[5]+red[6]+red[7];
            float mu = S * (1.0f/DD);
            float var = Q * (1.0f/DD) - mu*mu;
            red[8] = mu; red[9] = rsqrtf(var + 1e-5f);
        }
        __syncthreads();
        dst[tid] = (v - red[8]) * red[9] * g[tid] + bb[tid];
    } else {
        int base = (blk - 384) * 512;
        half2* wb = (half2*)(ws + WS_WB16);
        #pragma unroll
        for (int j = 0; j < 2; ++j) {
            int idx = base + j*256 + tid;      // 0..65535
            half2 h; h[0] = (_Float16)few[idx]; h[1] = (_Float16)feb[idx];
            wb[idx] = h;
        }
    }
}

// blocks 0..255: CW[n][k] = sum_d col_ln[n][d] * diw[d][256+k]  (f16)
// blocks 256..383: base[p][d] = sum_k LNp[p][k]*diw[d][k] + dib[d] + emb_prompt[p][d]
__global__ __launch_bounds__(256) void k0b(
    const float* __restrict__ diw, const float* __restrict__ dib,
    const float* __restrict__ emb_prompt, char* __restrict__ ws)
{
    __shared__ float rowv[DD];
    int blk = blockIdx.x, tid = threadIdx.x;
    if (blk < 256) {
        int n = blk;
        const float* col_ln = (const float*)(ws + WS_COL_LN);
        rowv[tid] = col_ln[n*DD + tid];
        __syncthreads();
        float acc = 0.f;
        #pragma unroll 4
        for (int d = 0; d < DD; ++d) acc += rowv[d] * diw[d*512 + 256 + tid];
        ((_Float16*)(ws + WS_CW16))[n*DD + tid] = (_Float16)acc;
    } else {
        int p = blk - 256;
        const float* lnp = (const float*)(ws + WS_LNP);
        rowv[tid] = lnp[p*DD + tid];
        __syncthreads();
        float acc = 0.f;
        #pragma unroll 4
        for (int k = 0; k < DD; ++k) acc += rowv[k] * diw[tid*512 + k];
        ((float*)(ws + WS_BASE))[p*DD + tid] = acc + dib[tid] + emb_prompt[p*DD + tid];
    }
}

// base_logits[p][n] = sum_d base[p][d] * col_ln[n][d]
__global__ __launch_bounds__(256) void k0c(char* __restrict__ ws)
{
    __shared__ float bs[DD];
    int p = blockIdx.x, n = threadIdx.x;
    const float* base   = (const float*)(ws + WS_BASE);
    const float* col_ln = (const float*)(ws + WS_COL_LN);
    bs[n] = base[p*DD + n];
    __syncthreads();
    float acc = 0.f;
    #pragma unroll 4
    for (int d = 0; d < DD; ++d) acc += bs[d] * col_ln[n*DD + d];
    ((float*)(ws + WS_BLOG))[p*DD + n] = acc;
}

// ============================ main kernel ============================
// 1 block = 1 batch. 8 waves, wave w owns prompt tile p in [16w,16w+16).
// Single accumulator array `acc` is reused: logits (P1/P2), then V (P3) —
// halves peak register pressure vs separate acc_l/acc_v.
__global__ __launch_bounds__(512, 2) void trompt_main(
    const float* __restrict__ x, const float* __restrict__ prev,
    const float* __restrict__ expand_w, const float* __restrict__ expand_b,
    const float* __restrict__ ln_emb_g, const float* __restrict__ ln_emb_b,
    const char* __restrict__ ws, float* __restrict__ out)
{
    extern __shared__ char smem[];
    float* x_s  = (float*)(smem);
    float* g_s  = (float*)(smem + 1024);
    float* bb_s = (float*)(smem + 2048);
    _Float16* xe0 = (_Float16*)(smem + XE0_OFF);
    _Float16* xe1 = (_Float16*)(smem + XE1_OFF);

    const char*  CW16 = ws + WS_CW16;                      // f16 [n][k]
    const half2* WB   = (const half2*)(ws + WS_WB16);      // [n][d] {w,b}
    const float* blog = (const float*)(ws + WS_BLOG);

    int b = blockIdx.x;
    int tid = threadIdx.x;
    int w = tid >> 6, l = tid & 63, lq = l >> 4, lr = l & 15;

    // --- accumulator union: logits now, V later ---
    f32x4 acc[16];
    {
        const float* blrow = blog + (16*w + lr)*DD + 4*lq;
        #pragma unroll
        for (int nt = 0; nt < 16; ++nt) acc[nt] = *(const f32x4*)(blrow + 16*nt);
    }

    if (tid < 256) {
        x_s[tid]  = x[b*NCOLS + tid];
        g_s[tid]  = ln_emb_g[tid];
        bb_s[tid] = ln_emb_b[tid];
    }
    __syncthreads();

    // ---------------- P1: logits^T += CW @ prev^T (K=16, barrier-free) ----------------
    {
        const char* cwlane = CW16 + lr*512 + lq*8;   // + nt*8192 + kc*32
        half4 af0[8], af1[8];
        #pragma unroll
        for (int i = 0; i < 8; ++i) af0[i] = *(const half4*)(cwlane + i*8192);
        #pragma unroll
        for (int i = 0; i < 8; ++i) af1[i] = *(const half4*)(cwlane + (8+i)*8192);

        const float* prow = prev + ((size_t)b*NP + 16*w + lr)*DD + 4*lq;
        f32x4 pb_c = *(const f32x4*)(prow);

        #pragma unroll
        for (int kc = 0; kc < 16; ++kc) {
            f32x4 pb_n;
            if (kc < 15) pb_n = *(const f32x4*)(prow + (kc+1)*16);
            half4 bp;
            #pragma unroll
            for (int j = 0; j < 4; ++j) bp[j] = (_Float16)pb_c[j];
            #pragma unroll
            for (int i = 0; i < 8; ++i) {
                half4 v = af0[i];
                if (kc < 15) af0[i] = *(const half4*)(cwlane + i*8192 + (kc+1)*32);
                acc[i] = MFMA16(v, bp, acc[i]);
            }
            #pragma unroll
            for (int i = 0; i < 8; ++i) {
                half4 v = af1[i];
                if (kc < 15) af1[i] = *(const half4*)(cwlane + (8+i)*8192 + (kc+1)*32);
                acc[8+i] = MFMA16(v, bp, acc[8+i]);
            }
            pb_c = pb_n;
        }
    }

    // x_emb tile compute (64 n-rows) into transposed LDS [d][n], 8 rows/wave.
    auto compute_xe = [&](int tile, _Float16* xb) {
        #pragma unroll
        for (int i = 0; i < 8; ++i) {
            int nloc = w + 8*i;
            int n = tile*64 + nloc;
            float xv = x_s[n];
            const half2* wbrow = WB + n*DD;
            float ev[4]; float s = 0.f, q = 0.f;
            #pragma unroll
            for (int c = 0; c < 4; ++c) {
                int d = l + 64*c;
                half2 p = wbrow[d];
                float e = fmaf(xv, (float)p[0], (float)p[1]);
                e = e > 0.f ? e : 0.f;
                ev[c] = e; s += e; q += e*e;
            }
            #pragma unroll
            for (int off = 32; off; off >>= 1) { s += __shfl_xor(s, off); q += __shfl_xor(q, off); }
            float mu = s * (1.0f/DD);
            float rs = rsqrtf(q*(1.0f/DD) - mu*mu + 1e-5f);
            #pragma unroll
            for (int c = 0; c < 4; ++c) {
                int d = l + 64*c;
                xb[d*XE_STRIDE + nloc] = (_Float16)((ev[c]-mu)*rs*g_s[d] + bb_s[d]);
            }
        }
    };

    // overlap xe tile-0 compute with softmax's shfl latency
    compute_xe(0, xe0);

    // ---------------- P2: softmax over n, normalize, convert to f16 B-fragments ----------------
    half4 p16[16];
    {
        float mx = -1e30f;
        #pragma unroll
        for (int nt = 0; nt < 16; ++nt)
            #pragma unroll
            for (int r = 0; r < 4; ++r) mx = fmaxf(mx, acc[nt][r]);
        mx = fmaxf(mx, __shfl_xor(mx, 16));
        mx = fmaxf(mx, __shfl_xor(mx, 32));
        float sum = 0.f;
        #pragma unroll
        for (int nt = 0; nt < 16; ++nt)
            #pragma unroll
            for (int r = 0; r < 4; ++r) { float e = __expf(acc[nt][r] - mx); acc[nt][r] = e; sum += e; }
        sum += __shfl_xor(sum, 16);
        sum += __shfl_xor(sum, 32);
        float inv = 1.0f / sum;
        #pragma unroll
        for (int nt = 0; nt < 16; ++nt) {
            half4 h;
            #pragma unroll
            for (int r = 0; r < 4; ++r) h[r] = (_Float16)(acc[nt][r] * inv);
            p16[nt] = h;
        }
    }

    // reset union accumulator for V
    #pragma unroll
    for (int dt = 0; dt < 16; ++dt) acc[dt] = (f32x4){0.f,0.f,0.f,0.f};

    __syncthreads();   // xe0 ready

    // ---------------- P3: V^T = xe^T @ P (K=16; xe tiles dbuf'd against MFMA) ----------------
    for (int t = 0; t < 4; ++t) {
        _Float16* xb = (t & 1) ? xe1 : xe0;
        if (t < 3) compute_xe(t+1, (t & 1) ? xe0 : xe1);
        #pragma unroll
        for (int kc2 = 0; kc2 < 4; ++kc2) {
            half4 bp = p16[4*t + kc2];
            #pragma unroll
            for (int dt = 0; dt < 16; ++dt) {
                half4 a = *(const half4*)(xb + (16*dt + lr)*XE_STRIDE + kc2*16 + lq*4);
                acc[dt] = MFMA16(a, bp, acc[dt]);
            }
        }
        __syncthreads();
    }

    // epilogue: D[d][p] orientation -> per-lane p uniform, f32x4 stores along d
    {
        int p = 16*w + lr;
        float sw = 1.0f + expand_w[p];
        float sb = expand_b[p];
        float* orow = out + ((size_t)b*NP + p)*DD + 4*lq;
        #pragma unroll
        for (int dt = 0; dt < 16; ++dt) {
            f32x4 v = acc[dt];
            #pragma unroll
            for (int r = 0; r < 4; ++r) v[r] = v[r]*sw + sb;
            *(f32x4*)(orow + 16*dt) = v;
        }
    }
}

// ============================ launcher ============================
extern "C" void kernel_launch(void* const* d_in, const int* in_sizes, int n_in,
                              void* d_out, int out_size, void* d_ws, size_t ws_size,
                              hipStream_t stream) {
    (void)in_sizes; (void)n_in; (void)out_size; (void)ws_size;
    const float* x           = (const float*)d_in[0];
    const float* prev        = (const float*)d_in[1];
    const float* few         = (const float*)d_in[2];
    const float* feb         = (const float*)d_in[3];
    const float* ln_emb_g    = (const float*)d_in[4];
    const float* ln_emb_b    = (const float*)d_in[5];
    const float* ln_col_g    = (const float*)d_in[6];
    const float* ln_col_b    = (const float*)d_in[7];
    const float* ln_prompt_g = (const float*)d_in[8];
    const float* ln_prompt_b = (const float*)d_in[9];
    const float* diw         = (const float*)d_in[10];
    const float* dib         = (const float*)d_in[11];
    const float* emb_column  = (const float*)d_in[12];
    const float* emb_prompt  = (const float*)d_in[13];
    const float* expand_w    = (const float*)d_in[14];
    const float* expand_b    = (const float*)d_in[15];
    char* ws = (char*)d_ws;
    float* out = (float*)d_out;

    k0a<<<512, 256, 0, stream>>>(emb_column, emb_prompt, ln_col_g, ln_col_b,
                                 ln_prompt_g, ln_prompt_b, few, feb, ws);
    k0b<<<384, 256, 0, stream>>>(diw, dib, emb_prompt, ws);
    k0c<<<128, 256, 0, stream>>>(ws);

    (void)hipFuncSetAttribute(reinterpret_cast<const void*>(trompt_main),
                              hipFuncAttributeMaxDynamicSharedMemorySize, SMEM_BYTES);
    trompt_main<<<1024, 512, SMEM_BYTES, stream>>>(x, prev, expand_w, expand_b,
                                                   ln_emb_g, ln_emb_b, ws, out);
}

// Round 5
// 338.081 us; speedup vs baseline: 1.9855x; 1.7653x over previous
//
#include <hip/hip_runtime.h>

#define NCOLS 256
#define NP    128
#define DD    256

typedef _Float16 half2 __attribute__((ext_vector_type(2)));
typedef _Float16 half4 __attribute__((ext_vector_type(4)));
typedef float    f32x4 __attribute__((ext_vector_type(4)));

// gfx950 spelling has no underscore before f16 (compiler-confirmed)
#define MFMA16(a,b,c) __builtin_amdgcn_mfma_f32_16x16x16f16(a,b,c,0,0,0)

// ---- workspace layout (bytes) ----
#define WS_COL_LN   0          // f32 [256][256]  LN(emb_column)
#define WS_LNP      262144     // f32 [128][256]  LN(emb_prompt)
#define WS_BASE     393216     // f32 [128][256]  base (prompt-side xp part)
#define WS_BLOG     524288     // f32 [128][256]  base_logits
#define WS_CW16     655360     // f16 CW in MFMA A-fragment order (see k0b)
#define WS_WB16     786432     // half2 [256][256] {w,b} interleaved feature emb

// ---- main-kernel LDS layout ----
#define XE_STRIDE 68           // f16 units; row byte stride 136 (8B aligned)
#define XE0_OFF   3072
#define XE1_OFF   37888
#define SMEM_BYTES 72704       // 2 blocks/CU: 2*72704 = 145408 <= 163840

// ============================ stage 0 kernels ============================

__global__ __launch_bounds__(256) void k0a(
    const float* __restrict__ emb_column, const float* __restrict__ emb_prompt,
    const float* __restrict__ ln_col_g, const float* __restrict__ ln_col_b,
    const float* __restrict__ ln_prompt_g, const float* __restrict__ ln_prompt_b,
    const float* __restrict__ few, const float* __restrict__ feb, char* __restrict__ ws)
{
    __shared__ float red[10];
    int blk = blockIdx.x, tid = threadIdx.x;
    if (blk < 384) {
        const float *src, *g, *bb; float* dst;
        if (blk < 256) { int r = blk;     src = emb_column + r*DD; g = ln_col_g;    bb = ln_col_b;    dst = (float*)(ws + WS_COL_LN) + r*DD; }
        else           { int r = blk-256; src = emb_prompt + r*DD; g = ln_prompt_g; bb = ln_prompt_b; dst = (float*)(ws + WS_LNP) + r*DD; }
        float v = src[tid];
        float s = v, q = v*v;
        #pragma unroll
        for (int off = 32; off; off >>= 1) { s += __shfl_xor(s, off); q += __shfl_xor(q, off); }
        int wid = tid >> 6, lane = tid & 63;
        if (lane == 0) { red[wid] = s; red[4+wid] = q; }
        __syncthreads();
        if (tid == 0) {
            float S = red[0]+red[1]+red[2]+red[3];
            float Q = red[4]+red[5]+red[6]+red[7];
            float mu = S * (1.0f/DD);
            float var = Q * (1.0f/DD) - mu*mu;
            red[8] = mu; red[9] = rsqrtf(var + 1e-5f);
        }
        __syncthreads();
        dst[tid] = (v - red[8]) * red[9] * g[tid] + bb[tid];
    } else {
        int base = (blk - 384) * 512;
        half2* wb = (half2*)(ws + WS_WB16);
        #pragma unroll
        for (int j = 0; j < 2; ++j) {
            int idx = base + j*256 + tid;      // 0..65535
            half2 h; h[0] = (_Float16)few[idx]; h[1] = (_Float16)feb[idx];
            wb[idx] = h;
        }
    }
}

// blocks 0..255: CW[n][k] = sum_d col_ln[n][d] * diw[d][256+k], stored in
//   MFMA A-fragment order: f16 index ((kc*16+nt)*64 + lq*16 + lr)*4 + j
//   with n = 16nt+lr, k = 16kc+4lq+j  -> P1 lane loads become contiguous.
// blocks 256..383: base[p][d] = sum_k LNp[p][k]*diw[d][k] + dib[d] + emb_prompt[p][d]
__global__ __launch_bounds__(256) void k0b(
    const float* __restrict__ diw, const float* __restrict__ dib,
    const float* __restrict__ emb_prompt, char* __restrict__ ws)
{
    __shared__ float rowv[DD];
    int blk = blockIdx.x, tid = threadIdx.x;
    if (blk < 256) {
        int n = blk;
        const float* col_ln = (const float*)(ws + WS_COL_LN);
        rowv[tid] = col_ln[n*DD + tid];
        __syncthreads();
        float acc = 0.f;
        #pragma unroll 4
        for (int d = 0; d < DD; ++d) acc += rowv[d] * diw[d*512 + 256 + tid];
        int nt = n >> 4, lr = n & 15;
        int kc = tid >> 4, lq = (tid >> 2) & 3, j = tid & 3;
        ((_Float16*)(ws + WS_CW16))[((kc*16 + nt)*64 + lq*16 + lr)*4 + j] = (_Float16)acc;
    } else {
        int p = blk - 256;
        const float* lnp = (const float*)(ws + WS_LNP);
        rowv[tid] = lnp[p*DD + tid];
        __syncthreads();
        float acc = 0.f;
        #pragma unroll 4
        for (int k = 0; k < DD; ++k) acc += rowv[k] * diw[tid*512 + k];
        ((float*)(ws + WS_BASE))[p*DD + tid] = acc + dib[tid] + emb_prompt[p*DD + tid];
    }
}

// base_logits[p][n] = sum_d base[p][d] * col_ln[n][d]
__global__ __launch_bounds__(256) void k0c(char* __restrict__ ws)
{
    __shared__ float bs[DD];
    int p = blockIdx.x, n = threadIdx.x;
    const float* base   = (const float*)(ws + WS_BASE);
    const float* col_ln = (const float*)(ws + WS_COL_LN);
    bs[n] = base[p*DD + n];
    __syncthreads();
    float acc = 0.f;
    #pragma unroll 4
    for (int d = 0; d < DD; ++d) acc += bs[d] * col_ln[n*DD + d];
    ((float*)(ws + WS_BLOG))[p*DD + n] = acc;
}

// ============================ main kernel ============================
// 1 block = 1 batch. 8 waves, wave w owns prompt tile p in [16w,16w+16).
// Single accumulator array `acc` reused: logits (P1/P2) then V (P3).
// CW loaded from ws in fragment order (coalesced 512B/wave/fragment).
__global__ __launch_bounds__(512, 4) void trompt_main(
    const float* __restrict__ x, const float* __restrict__ prev,
    const float* __restrict__ expand_w, const float* __restrict__ expand_b,
    const float* __restrict__ ln_emb_g, const float* __restrict__ ln_emb_b,
    const char* __restrict__ ws, float* __restrict__ out)
{
    extern __shared__ char smem[];
    float* x_s  = (float*)(smem);
    float* g_s  = (float*)(smem + 1024);
    float* bb_s = (float*)(smem + 2048);
    _Float16* xe0 = (_Float16*)(smem + XE0_OFF);
    _Float16* xe1 = (_Float16*)(smem + XE1_OFF);

    const char*  CWF  = ws + WS_CW16;                      // fragment-ordered
    const half2* WB   = (const half2*)(ws + WS_WB16);      // [n][d] {w,b}
    const float* blog = (const float*)(ws + WS_BLOG);

    int b = blockIdx.x;
    int tid = threadIdx.x;
    int w = tid >> 6, l = tid & 63, lq = l >> 4, lr = l & 15;

    // --- accumulator union: logits now, V later; C-init from base_logits ---
    f32x4 acc[16];
    {
        const float* blrow = blog + (16*w + lr)*DD + 4*lq;
        #pragma unroll
        for (int nt = 0; nt < 16; ++nt) acc[nt] = *(const f32x4*)(blrow + 16*nt);
    }

    if (tid < 256) {
        x_s[tid]  = x[b*NCOLS + tid];
        g_s[tid]  = ln_emb_g[tid];
        bb_s[tid] = ln_emb_b[tid];
    }
    __syncthreads();

    // ---------------- P1: logits^T += CW @ prev^T (K=16, barrier-free) ----------------
    {
        const char* cwlane = CWF + l*8;      // + (kc*16 + nt)*512
        const float* prow = prev + ((size_t)b*NP + 16*w + lr)*DD + 4*lq;

        half4 af[8], ag[8];
        #pragma unroll
        for (int i = 0; i < 8; ++i) af[i] = *(const half4*)(cwlane + i*512);
        f32x4 pb_c = *(const f32x4*)(prow);

        for (int kc = 0; kc < 16; ++kc) {
            // issue second-half fragment loads for this kc
            #pragma unroll
            for (int i = 0; i < 8; ++i) ag[i] = *(const half4*)(cwlane + (kc*16 + 8 + i)*512);
            f32x4 pb_n;
            if (kc < 15) pb_n = *(const f32x4*)(prow + (kc+1)*16);
            half4 bp;
            #pragma unroll
            for (int j = 0; j < 4; ++j) bp[j] = (_Float16)pb_c[j];
            #pragma unroll
            for (int i = 0; i < 8; ++i) {
                half4 v = af[i];
                if (kc < 15) af[i] = *(const half4*)(cwlane + ((kc+1)*16 + i)*512);
                acc[i] = MFMA16(v, bp, acc[i]);
            }
            #pragma unroll
            for (int i = 0; i < 8; ++i)
                acc[8+i] = MFMA16(ag[i], bp, acc[8+i]);
            pb_c = pb_n;
        }
    }

    // x_emb tile compute (64 n-rows) into transposed LDS [d][n], 8 rows/wave.
    auto compute_xe = [&](int tile, _Float16* xb) {
        #pragma unroll
        for (int i = 0; i < 8; ++i) {
            int nloc = w + 8*i;
            int n = tile*64 + nloc;
            float xv = x_s[n];
            const half2* wbrow = WB + n*DD;
            float ev[4]; float s = 0.f, q = 0.f;
            #pragma unroll
            for (int c = 0; c < 4; ++c) {
                int d = l + 64*c;
                half2 p = wbrow[d];
                float e = fmaf(xv, (float)p[0], (float)p[1]);
                e = e > 0.f ? e : 0.f;
                ev[c] = e; s += e; q += e*e;
            }
            #pragma unroll
            for (int off = 32; off; off >>= 1) { s += __shfl_xor(s, off); q += __shfl_xor(q, off); }
            float mu = s * (1.0f/DD);
            float rs = rsqrtf(q*(1.0f/DD) - mu*mu + 1e-5f);
            #pragma unroll
            for (int c = 0; c < 4; ++c) {
                int d = l + 64*c;
                xb[d*XE_STRIDE + nloc] = (_Float16)((ev[c]-mu)*rs*g_s[d] + bb_s[d]);
            }
        }
    };

    // overlap xe tile-0 compute with softmax's shfl latency
    compute_xe(0, xe0);

    // ---------------- P2: softmax over n, normalize, convert to f16 B-fragments ----------------
    half4 p16[16];
    {
        float mx = -1e30f;
        #pragma unroll
        for (int nt = 0; nt < 16; ++nt)
            #pragma unroll
            for (int r = 0; r < 4; ++r) mx = fmaxf(mx, acc[nt][r]);
        mx = fmaxf(mx, __shfl_xor(mx, 16));
        mx = fmaxf(mx, __shfl_xor(mx, 32));
        float sum = 0.f;
        #pragma unroll
        for (int nt = 0; nt < 16; ++nt)
            #pragma unroll
            for (int r = 0; r < 4; ++r) { float e = __expf(acc[nt][r] - mx); acc[nt][r] = e; sum += e; }
        sum += __shfl_xor(sum, 16);
        sum += __shfl_xor(sum, 32);
        float inv = 1.0f / sum;
        #pragma unroll
        for (int nt = 0; nt < 16; ++nt) {
            half4 h;
            #pragma unroll
            for (int r = 0; r < 4; ++r) h[r] = (_Float16)(acc[nt][r] * inv);
            p16[nt] = h;
        }
    }

    // reset union accumulator for V
    #pragma unroll
    for (int dt = 0; dt < 16; ++dt) acc[dt] = (f32x4){0.f,0.f,0.f,0.f};

    __syncthreads();   // xe0 ready

    // ---------------- P3: V^T = xe^T @ P (K=16; xe tiles dbuf'd against MFMA) ----------------
    for (int t = 0; t < 4; ++t) {
        _Float16* xb = (t & 1) ? xe1 : xe0;
        if (t < 3) compute_xe(t+1, (t & 1) ? xe0 : xe1);
        #pragma unroll
        for (int kc2 = 0; kc2 < 4; ++kc2) {
            half4 bp = p16[4*t + kc2];
            #pragma unroll
            for (int dt = 0; dt < 16; ++dt) {
                half4 a = *(const half4*)(xb + (16*dt + lr)*XE_STRIDE + kc2*16 + lq*4);
                acc[dt] = MFMA16(a, bp, acc[dt]);
            }
        }
        __syncthreads();
    }

    // epilogue: D[d][p] orientation -> per-lane p uniform, f32x4 stores along d
    {
        int p = 16*w + lr;
        float sw = 1.0f + expand_w[p];
        float sb = expand_b[p];
        float* orow = out + ((size_t)b*NP + p)*DD + 4*lq;
        #pragma unroll
        for (int dt = 0; dt < 16; ++dt) {
            f32x4 v = acc[dt];
            #pragma unroll
            for (int r = 0; r < 4; ++r) v[r] = v[r]*sw + sb;
            *(f32x4*)(orow + 16*dt) = v;
        }
    }
}

// ============================ launcher ============================
extern "C" void kernel_launch(void* const* d_in, const int* in_sizes, int n_in,
                              void* d_out, int out_size, void* d_ws, size_t ws_size,
                              hipStream_t stream) {
    (void)in_sizes; (void)n_in; (void)out_size; (void)ws_size;
    const float* x           = (const float*)d_in[0];
    const float* prev        = (const float*)d_in[1];
    const float* few         = (const float*)d_in[2];
    const float* feb         = (const float*)d_in[3];
    const float* ln_emb_g    = (const float*)d_in[4];
    const float* ln_emb_b    = (const float*)d_in[5];
    const float* ln_col_g    = (const float*)d_in[6];
    const float* ln_col_b    = (const float*)d_in[7];
    const float* ln_prompt_g = (const float*)d_in[8];
    const float* ln_prompt_b = (const float*)d_in[9];
    const float* diw         = (const float*)d_in[10];
    const float* dib         = (const float*)d_in[11];
    const float* emb_column  = (const float*)d_in[12];
    const float* emb_prompt  = (const float*)d_in[13];
    const float* expand_w    = (const float*)d_in[14];
    const float* expand_b    = (const float*)d_in[15];
    char* ws = (char*)d_ws;
    float* out = (float*)d_out;

    k0a<<<512, 256, 0, stream>>>(emb_column, emb_prompt, ln_col_g, ln_col_b,
                                 ln_prompt_g, ln_prompt_b, few, feb, ws);
    k0b<<<384, 256, 0, stream>>>(diw, dib, emb_prompt, ws);
    k0c<<<128, 256, 0, stream>>>(ws);

    (void)hipFuncSetAttribute(reinterpret_cast<const void*>(trompt_main),
                              hipFuncAttributeMaxDynamicSharedMemorySize, SMEM_BYTES);
    trompt_main<<<1024, 512, SMEM_BYTES, stream>>>(x, prev, expand_w, expand_b,
                                                   ln_emb_g, ln_emb_b, ws, out);
}

// Round 6
// 265.709 us; speedup vs baseline: 2.5263x; 1.2724x over previous
//
#include <hip/hip_runtime.h>

#define NCOLS 256
#define NP    128
#define DD    256

typedef _Float16 half2 __attribute__((ext_vector_type(2)));
typedef _Float16 half4 __attribute__((ext_vector_type(4)));
typedef float    f32x4 __attribute__((ext_vector_type(4)));

// gfx950 spelling has no underscore before f16 (compiler-confirmed)
#define MFMA16(a,b,c) __builtin_amdgcn_mfma_f32_16x16x16f16(a,b,c,0,0,0)

// ---- workspace layout (bytes) ----
#define WS_COL_LN   0          // f32 [256][256]  LN(emb_column)
#define WS_LNP      262144     // f32 [128][256]  LN(emb_prompt)
#define WS_BASE     393216     // f32 [128][256]  base (prompt-side xp part)
#define WS_BLOG     524288     // f32 [128][256]  base_logits
#define WS_CW16     655360     // f16 CW in MFMA A-fragment order (see k0b)
#define WS_WB16     786432     // half2 [256][256] {w,b} interleaved feature emb

// ---- main-kernel LDS layout ----
#define XE_STRIDE 68           // f16 units; row byte stride 136 (8B aligned)
#define XE0_OFF   3072
#define XE1_OFF   37888
#define SMEM_BYTES 72704       // 2 blocks/CU: 2*72704 = 145408 <= 163840

// ============================ stage 0 kernels ============================

__global__ __launch_bounds__(256) void k0a(
    const float* __restrict__ emb_column, const float* __restrict__ emb_prompt,
    const float* __restrict__ ln_col_g, const float* __restrict__ ln_col_b,
    const float* __restrict__ ln_prompt_g, const float* __restrict__ ln_prompt_b,
    const float* __restrict__ few, const float* __restrict__ feb, char* __restrict__ ws)
{
    __shared__ float red[10];
    int blk = blockIdx.x, tid = threadIdx.x;
    if (blk < 384) {
        const float *src, *g, *bb; float* dst;
        if (blk < 256) { int r = blk;     src = emb_column + r*DD; g = ln_col_g;    bb = ln_col_b;    dst = (float*)(ws + WS_COL_LN) + r*DD; }
        else           { int r = blk-256; src = emb_prompt + r*DD; g = ln_prompt_g; bb = ln_prompt_b; dst = (float*)(ws + WS_LNP) + r*DD; }
        float v = src[tid];
        float s = v, q = v*v;
        #pragma unroll
        for (int off = 32; off; off >>= 1) { s += __shfl_xor(s, off); q += __shfl_xor(q, off); }
        int wid = tid >> 6, lane = tid & 63;
        if (lane == 0) { red[wid] = s; red[4+wid] = q; }
        __syncthreads();
        if (tid == 0) {
            float S = red[0]+red[1]+red[2]+red[3];
            float Q = red[4]+red[5]+red[6]+red[7];
            float mu = S * (1.0f/DD);
            float var = Q * (1.0f/DD) - mu*mu;
            red[8] = mu; red[9] = rsqrtf(var + 1e-5f);
        }
        __syncthreads();
        dst[tid] = (v - red[8]) * red[9] * g[tid] + bb[tid];
    } else {
        int base = (blk - 384) * 512;
        half2* wb = (half2*)(ws + WS_WB16);
        #pragma unroll
        for (int j = 0; j < 2; ++j) {
            int idx = base + j*256 + tid;      // 0..65535
            half2 h; h[0] = (_Float16)few[idx]; h[1] = (_Float16)feb[idx];
            wb[idx] = h;
        }
    }
}

// blocks 0..255: CW[n][k] = sum_d col_ln[n][d] * diw[d][256+k], stored in
//   MFMA A-fragment order: f16 index ((kc*16+nt)*64 + lq*16 + lr)*4 + j
//   with n = 16nt+lr, k = 16kc+4lq+j  -> P1 lane loads become contiguous.
// blocks 256..383: base[p][d] = sum_k LNp[p][k]*diw[d][k] + dib[d] + emb_prompt[p][d]
__global__ __launch_bounds__(256) void k0b(
    const float* __restrict__ diw, const float* __restrict__ dib,
    const float* __restrict__ emb_prompt, char* __restrict__ ws)
{
    __shared__ float rowv[DD];
    int blk = blockIdx.x, tid = threadIdx.x;
    if (blk < 256) {
        int n = blk;
        const float* col_ln = (const float*)(ws + WS_COL_LN);
        rowv[tid] = col_ln[n*DD + tid];
        __syncthreads();
        float acc = 0.f;
        #pragma unroll 4
        for (int d = 0; d < DD; ++d) acc += rowv[d] * diw[d*512 + 256 + tid];
        int nt = n >> 4, lr = n & 15;
        int kc = tid >> 4, lq = (tid >> 2) & 3, j = tid & 3;
        ((_Float16*)(ws + WS_CW16))[((kc*16 + nt)*64 + lq*16 + lr)*4 + j] = (_Float16)acc;
    } else {
        int p = blk - 256;
        const float* lnp = (const float*)(ws + WS_LNP);
        rowv[tid] = lnp[p*DD + tid];
        __syncthreads();
        float acc = 0.f;
        #pragma unroll 4
        for (int k = 0; k < DD; ++k) acc += rowv[k] * diw[tid*512 + k];
        ((float*)(ws + WS_BASE))[p*DD + tid] = acc + dib[tid] + emb_prompt[p*DD + tid];
    }
}

// base_logits[p][n] = sum_d base[p][d] * col_ln[n][d]
__global__ __launch_bounds__(256) void k0c(char* __restrict__ ws)
{
    __shared__ float bs[DD];
    int p = blockIdx.x, n = threadIdx.x;
    const float* base   = (const float*)(ws + WS_BASE);
    const float* col_ln = (const float*)(ws + WS_COL_LN);
    bs[n] = base[p*DD + n];
    __syncthreads();
    float acc = 0.f;
    #pragma unroll 4
    for (int d = 0; d < DD; ++d) acc += bs[d] * col_ln[n*DD + d];
    ((float*)(ws + WS_BLOG))[p*DD + n] = acc;
}

// ============================ main kernel ============================
// 1 block = 1 batch. 8 waves, wave w owns prompt rows p in [16w,16w+16).
// Flash-style: n processed in 4 chunks of 64; per chunk {logits sub-tile,
// online-softmax update (running m,l + V rescale), f16 P chunk, PV MFMA
// against the chunk's xe tile}. Full P never materialized -> no spill at
// the 128-reg cap of (512,4).
__global__ __launch_bounds__(512, 4) void trompt_main(
    const float* __restrict__ x, const float* __restrict__ prev,
    const float* __restrict__ expand_w, const float* __restrict__ expand_b,
    const float* __restrict__ ln_emb_g, const float* __restrict__ ln_emb_b,
    const char* __restrict__ ws, float* __restrict__ out)
{
    extern __shared__ char smem[];
    float* x_s  = (float*)(smem);
    float* g_s  = (float*)(smem + 1024);
    float* bb_s = (float*)(smem + 2048);
    _Float16* xe0 = (_Float16*)(smem + XE0_OFF);
    _Float16* xe1 = (_Float16*)(smem + XE1_OFF);

    const char*  CWF  = ws + WS_CW16;                      // fragment-ordered
    const half2* WB   = (const half2*)(ws + WS_WB16);      // [n][d] {w,b}
    const float* blog = (const float*)(ws + WS_BLOG);

    int b = blockIdx.x;
    int tid = threadIdx.x;
    int w = tid >> 6, l = tid & 63, lq = l >> 4, lr = l & 15;

    if (tid < 256) {
        x_s[tid]  = x[b*NCOLS + tid];
        g_s[tid]  = ln_emb_g[tid];
        bb_s[tid] = ln_emb_b[tid];
    }

    // prev row -> f16 B-fragments, held for all 4 chunks (32 VGPRs)
    half4 pfrag[16];
    {
        const float* prow = prev + ((size_t)b*NP + 16*w + lr)*DD + 4*lq;
        #pragma unroll
        for (int kc = 0; kc < 16; ++kc) {
            f32x4 v = *(const f32x4*)(prow + 16*kc);
            half4 h;
            #pragma unroll
            for (int j = 0; j < 4; ++j) h[j] = (_Float16)v[j];
            pfrag[kc] = h;
        }
    }
    __syncthreads();            // x_s ready

    // x_emb tile compute (64 n-rows) into transposed LDS [d][nloc], 8 rows/wave.
    auto compute_xe = [&](int tile, _Float16* xb) {
        #pragma unroll
        for (int i = 0; i < 8; ++i) {
            int nloc = w + 8*i;
            int n = tile*64 + nloc;
            float xv = x_s[n];
            const half2* wbrow = WB + n*DD;
            float ev[4]; float s = 0.f, q = 0.f;
            #pragma unroll
            for (int c = 0; c < 4; ++c) {
                int d = l + 64*c;
                half2 p = wbrow[d];
                float e = fmaf(xv, (float)p[0], (float)p[1]);
                e = e > 0.f ? e : 0.f;
                ev[c] = e; s += e; q += e*e;
            }
            #pragma unroll
            for (int off = 32; off; off >>= 1) { s += __shfl_xor(s, off); q += __shfl_xor(q, off); }
            float mu = s * (1.0f/DD);
            float rs = rsqrtf(q*(1.0f/DD) - mu*mu + 1e-5f);
            #pragma unroll
            for (int c = 0; c < 4; ++c) {
                int d = l + 64*c;
                xb[d*XE_STRIDE + nloc] = (_Float16)((ev[c]-mu)*rs*g_s[d] + bb_s[d]);
            }
        }
    };

    compute_xe(0, xe0);

    f32x4 acc_v[16];
    #pragma unroll
    for (int dt = 0; dt < 16; ++dt) acc_v[dt] = (f32x4){0.f,0.f,0.f,0.f};
    float m = -1e30f, ll = 0.f;

    __syncthreads();            // xe0 ready

    const char*  cwlane = CWF + l*8;
    const float* blrow  = blog + (16*w + lr)*DD + 4*lq;

    for (int c = 0; c < 4; ++c) {
        _Float16* xcur = (c & 1) ? xe1 : xe0;
        _Float16* xnxt = (c & 1) ? xe0 : xe1;

        // ---- logits chunk: 16p x 64n, C-init from base_logits ----
        f32x4 acc_c[4];
        #pragma unroll
        for (int nt = 0; nt < 4; ++nt) acc_c[nt] = *(const f32x4*)(blrow + 64*c + 16*nt);
        #pragma unroll
        for (int kc = 0; kc < 16; ++kc) {
            const char* fb = cwlane + (size_t)(kc*16 + 4*c)*512;
            half4 a0 = *(const half4*)(fb);
            half4 a1 = *(const half4*)(fb + 512);
            half4 a2 = *(const half4*)(fb + 1024);
            half4 a3 = *(const half4*)(fb + 1536);
            half4 bp = pfrag[kc];
            acc_c[0] = MFMA16(a0, bp, acc_c[0]);
            acc_c[1] = MFMA16(a1, bp, acc_c[1]);
            acc_c[2] = MFMA16(a2, bp, acc_c[2]);
            acc_c[3] = MFMA16(a3, bp, acc_c[3]);
        }

        // ---- online softmax update (row p is lane-local across lq: 2 shfls) ----
        float pmax = -1e30f;
        #pragma unroll
        for (int nt = 0; nt < 4; ++nt)
            #pragma unroll
            for (int r = 0; r < 4; ++r) pmax = fmaxf(pmax, acc_c[nt][r]);
        pmax = fmaxf(pmax, __shfl_xor(pmax, 16));
        pmax = fmaxf(pmax, __shfl_xor(pmax, 32));
        float mnew = fmaxf(m, pmax);
        float f = __expf(m - mnew);      // 0 on first chunk (m=-1e30), 1 if no change
        m = mnew;
        ll *= f;
        #pragma unroll
        for (int dt = 0; dt < 16; ++dt)
            #pragma unroll
            for (int r = 0; r < 4; ++r) acc_v[dt][r] *= f;

        float csum = 0.f;
        half4 p16c[4];
        #pragma unroll
        for (int nt = 0; nt < 4; ++nt) {
            half4 h;
            #pragma unroll
            for (int r = 0; r < 4; ++r) {
                float e = __expf(acc_c[nt][r] - m);
                csum += e;
                h[r] = (_Float16)e;
            }
            p16c[nt] = h;
        }
        csum += __shfl_xor(csum, 16);
        csum += __shfl_xor(csum, 32);
        ll += csum;

        // overlap next xe tile compute with this chunk's PV issue window
        if (c < 3) compute_xe(c+1, xnxt);

        // ---- PV: acc_v += xe_chunk^T @ P_chunk (4 K=16 slices) ----
        #pragma unroll
        for (int kc2 = 0; kc2 < 4; ++kc2) {
            half4 bp = p16c[kc2];
            #pragma unroll
            for (int dt = 0; dt < 16; ++dt) {
                half4 a = *(const half4*)(xcur + (16*dt + lr)*XE_STRIDE + kc2*16 + lq*4);
                acc_v[dt] = MFMA16(a, bp, acc_v[dt]);
            }
        }
        __syncthreads();
    }

    // epilogue: out = (V/ll)*sw + sb; D col = p (lane lr), rows d = 16dt+4lq+r
    {
        int p = 16*w + lr;
        float sw = (1.0f + expand_w[p]) / ll;
        float sb = expand_b[p];
        float* orow = out + ((size_t)b*NP + p)*DD + 4*lq;
        #pragma unroll
        for (int dt = 0; dt < 16; ++dt) {
            f32x4 v = acc_v[dt];
            #pragma unroll
            for (int r = 0; r < 4; ++r) v[r] = v[r]*sw + sb;
            *(f32x4*)(orow + 16*dt) = v;
        }
    }
}

// ============================ launcher ============================
extern "C" void kernel_launch(void* const* d_in, const int* in_sizes, int n_in,
                              void* d_out, int out_size, void* d_ws, size_t ws_size,
                              hipStream_t stream) {
    (void)in_sizes; (void)n_in; (void)out_size; (void)ws_size;
    const float* x           = (const float*)d_in[0];
    const float* prev        = (const float*)d_in[1];
    const float* few         = (const float*)d_in[2];
    const float* feb         = (const float*)d_in[3];
    const float* ln_emb_g    = (const float*)d_in[4];
    const float* ln_emb_b    = (const float*)d_in[5];
    const float* ln_col_g    = (const float*)d_in[6];
    const float* ln_col_b    = (const float*)d_in[7];
    const float* ln_prompt_g = (const float*)d_in[8];
    const float* ln_prompt_b = (const float*)d_in[9];
    const float* diw         = (const float*)d_in[10];
    const float* dib         = (const float*)d_in[11];
    const float* emb_column  = (const float*)d_in[12];
    const float* emb_prompt  = (const float*)d_in[13];
    const float* expand_w    = (const float*)d_in[14];
    const float* expand_b    = (const float*)d_in[15];
    char* ws = (char*)d_ws;
    float* out = (float*)d_out;

    k0a<<<512, 256, 0, stream>>>(emb_column, emb_prompt, ln_col_g, ln_col_b,
                                 ln_prompt_g, ln_prompt_b, few, feb, ws);
    k0b<<<384, 256, 0, stream>>>(diw, dib, emb_prompt, ws);
    k0c<<<128, 256, 0, stream>>>(ws);

    (void)hipFuncSetAttribute(reinterpret_cast<const void*>(trompt_main),
                              hipFuncAttributeMaxDynamicSharedMemorySize, SMEM_BYTES);
    trompt_main<<<1024, 512, SMEM_BYTES, stream>>>(x, prev, expand_w, expand_b,
                                                   ln_emb_g, ln_emb_b, ws, out);
}